// Round 6
// baseline (338.098 us; speedup 1.0000x reference)
//
#include <hip/hip_runtime.h>

typedef float f32x4 __attribute__((ext_vector_type(4)));
typedef __bf16 bf16x8 __attribute__((ext_vector_type(8)));
typedef __bf16 bf16x4 __attribute__((ext_vector_type(4)));

#define GLOBAL_AS __attribute__((address_space(1)))
#define LDS_AS    __attribute__((address_space(3)))

static __device__ __forceinline__ void gload16(const void* g, void* l) {
  __builtin_amdgcn_global_load_lds((const GLOBAL_AS void*)g, (LDS_AS void*)l, 16, 0, 0);
}

#define BAR() __builtin_amdgcn_s_barrier()
#define WAITL0() do { asm volatile("s_waitcnt lgkmcnt(0)" ::: "memory"); __builtin_amdgcn_sched_barrier(0); } while (0)

// ---- fused: Xb = bf16(X); XAb = bf16(X @ lora_A) [8192][64], cols>=16 zero --
__global__ __launch_bounds__(256)
void xa_cvt(const float* __restrict__ X, const float* __restrict__ A,
            __bf16* __restrict__ Xb, __bf16* __restrict__ XAb) {
  constexpr int K = 4096, TM = 16, KC = 64;
  __shared__ float Xs[TM][68];
  __shared__ float At[16][68];
  const int t = threadIdx.x;
  const int m0 = blockIdx.x * TM;
  const int lrow = t >> 4, c4 = (t & 15) * 4;
  const int orow = t >> 4, oc = t & 15;
  const int akk = t >> 2, ar4 = (t & 3) * 4;
  f32x4 av = (f32x4)0.f;
  for (int k0 = 0; k0 < K; k0 += KC) {
    const float* gx = X + (size_t)(m0 + lrow) * K + k0 + c4;
    f32x4 u = *reinterpret_cast<const f32x4*>(gx);
    *reinterpret_cast<f32x4*>(&Xs[lrow][c4]) = u;
    bf16x4 p;
#pragma unroll
    for (int e = 0; e < 4; ++e) p[e] = (__bf16)u[e];
    *reinterpret_cast<bf16x4*>(Xb + (size_t)(m0 + lrow) * K + k0 + c4) = p;
    f32x4 a = *reinterpret_cast<const f32x4*>(A + (size_t)(k0 + akk) * 16 + ar4);
    At[ar4 + 0][akk] = a[0]; At[ar4 + 1][akk] = a[1];
    At[ar4 + 2][akk] = a[2]; At[ar4 + 3][akk] = a[3];
    __syncthreads();
#pragma unroll
    for (int q = 0; q < 16; ++q) {
      f32x4 xv = *reinterpret_cast<const f32x4*>(&Xs[orow][q * 4]);
      av += xv * *reinterpret_cast<const f32x4*>(&At[oc][q * 4]);
    }
    __syncthreads();
  }
  const float acc = av[0] + av[1] + av[2] + av[3];
  const size_t base = (size_t)(m0 + orow) * 64;
  XAb[base + oc] = (__bf16)acc;
#pragma unroll
  for (int z = 0; z < 3; ++z) XAb[base + 16 + z * 16 + oc] = (__bf16)0.f;
}

// ---------------- W -> bf16 (16B stores) ----------------
__global__ __launch_bounds__(256)
void cvt_f32_bf16(const float* __restrict__ in, __bf16* __restrict__ out, long n8) {
  long i = (long)blockIdx.x * blockDim.x + threadIdx.x;
  long stride = (long)gridDim.x * blockDim.x;
  for (; i < n8; i += stride) {
    f32x4 u = reinterpret_cast<const f32x4*>(in)[2 * i];
    f32x4 v = reinterpret_cast<const f32x4*>(in)[2 * i + 1];
    bf16x8 p;
#pragma unroll
    for (int e = 0; e < 4; ++e) { p[e] = (__bf16)u[e]; p[4 + e] = (__bf16)v[e]; }
    reinterpret_cast<bf16x8*>(out)[i] = p;
  }
}

// ------- BlT[col][k] = bf16(Bl[k][col]), [4096][64], k>=16 zero -------------
__global__ __launch_bounds__(256)
void blt64(const float* __restrict__ Bl, __bf16* __restrict__ BlT) {
  int idx = blockIdx.x * 256 + threadIdx.x;
  int col = idx >> 6, k = idx & 63;
  float v = (k < 16) ? Bl[(size_t)k * 4096 + col] : 0.f;
  BlT[idx] = (__bf16)v;
}

// ---------------- 256x256 8-phase GEMM: out = [Xb|XAb] @ [Wb|BlT]^T + b -----
// 8 waves (2Mx4N), BK=64, zero-conflict XOR swizzle. Max-slack 2-ahead ledger:
// tile t stages B0,B1(t+2)@P3 (B(t) region free after P2 barrier) and
// A0,A1(t+2)@P4 (A(t) region free after P3 barrier); single vmcnt(8)/tile
// retires exactly {B(t+1),A(t+1)} issued 4-6 phases earlier.
__global__ __launch_bounds__(512, 2)
void gemm8(const __bf16* __restrict__ Xb, const __bf16* __restrict__ Wb,
           const __bf16* __restrict__ XAb, const __bf16* __restrict__ BlT,
           const float* __restrict__ bias, float* __restrict__ out) {
  constexpr int N = 4096, K = 4096;
  __shared__ __align__(16) char sm[131072];
  char* Asm_ = sm;
  char* Bsm_ = sm + 65536;

  const int t = threadIdx.x;
  const int lane = t & 63, w = t >> 6;
  const int wr = w >> 2, wc = w & 3;
  const int fr = lane & 15, fg = lane >> 4;

  // bijective XCD swizzle: grid 512 = 32 mt x 16 nt; 2-mt inner group.
  const int bid = blockIdx.x;
  const int xcd = bid & 7, l = bid >> 3;
  const int mt = (xcd << 2) | ((l >> 4) & 2) | (l & 1);
  const int nt = (l >> 1) & 15;
  const int m0 = mt * 256, n0 = nt * 256;

  const int sRow = w * 16 + (lane >> 2);
  const int sColB = (((lane & 3) ^ ((lane >> 3) & 3)) << 4);   // inverse swizzle
  const int rdOff = fr * 64 + ((fg ^ ((fr >> 1) & 3)) << 4);
  const int rdOffA = wr * 16384 + rdOff;
  const int rdOffB = (wc >> 1) * 16384 + (wc & 1) * 8192 + rdOff;

  auto stageA = [&](int h, int tt) {
    char* dst = Asm_ + (tt & 1) * 32768 + h * 16384 + w * 2048;
    const char* g;
    if (tt < 64) g = (const char*)(Xb + (size_t)(m0 + h * 128 + sRow) * K + (size_t)tt * 64) + sColB;
    else         g = (const char*)(XAb + (size_t)(m0 + h * 128 + sRow) * 64) + sColB;
    gload16(g, dst);
    gload16(g + 64, dst + 1024);
  };
  auto stageB = [&](int h, int tt) {
    char* dst = Bsm_ + (tt & 1) * 32768 + h * 16384 + w * 2048;
    const char* g;
    if (tt < 64) g = (const char*)(Wb + (size_t)(n0 + h * 128 + sRow) * K + (size_t)tt * 64) + sColB;
    else         g = (const char*)(BlT + (size_t)(n0 + h * 128 + sRow) * 64) + sColB;
    gload16(g, dst);
    gload16(g + 64, dst + 1024);
  };

  auto rdA = [&](int b, int mf, int kk) -> bf16x8 {
    return *reinterpret_cast<const bf16x8*>(Asm_ + b * 32768 + (mf * 2 + kk) * 1024 + rdOffA);
  };
  auto rdB = [&](int b, int nf, int kk) -> bf16x8 {
    return *reinterpret_cast<const bf16x8*>(Bsm_ + b * 32768 + (nf * 2 + kk) * 1024 + rdOffB);
  };

  f32x4 acc[8][4];
#pragma unroll
  for (int i = 0; i < 8; ++i)
#pragma unroll
    for (int j = 0; j < 4; ++j) acc[i][j] = (f32x4)0.f;

  bf16x8 aF[4][2], bL[2][2], bH[2][2];

  auto MF = [&](bf16x8 (&af)[4][2], bf16x8 (&bf_)[2][2], int mi, int ni) {
#pragma unroll
    for (int i = 0; i < 4; ++i)
#pragma unroll
      for (int j = 0; j < 2; ++j)
#pragma unroll
        for (int kk = 0; kk < 2; ++kk)
          acc[mi * 4 + i][ni * 2 + j] = __builtin_amdgcn_mfma_f32_16x16x32_bf16(
              af[i][kk], bf_[j][kk], acc[mi * 4 + i][ni * 2 + j], 0, 0, 0);
  };

  // steady tile t: stages B0,B1(t+2)@P3; A0,A1(t+2)@P4; vmcnt(8)
  auto tile_step = [&](int tv) {
    const int b = tv & 1;
    // P1: 12 ds_reads (A mf0..3, B nf0..1)
#pragma unroll
    for (int i = 0; i < 4; ++i)
#pragma unroll
      for (int kk = 0; kk < 2; ++kk) aF[i][kk] = rdA(b, i, kk);
#pragma unroll
    for (int j = 0; j < 2; ++j)
#pragma unroll
      for (int kk = 0; kk < 2; ++kk) bL[j][kk] = rdB(b, j, kk);
    BAR(); WAITL0();
    __builtin_amdgcn_s_setprio(1); MF(aF, bL, 0, 0); __builtin_amdgcn_s_setprio(0);
    BAR();
    // P2: 4 reads (B nf2..3)
#pragma unroll
    for (int j = 0; j < 2; ++j)
#pragma unroll
      for (int kk = 0; kk < 2; ++kk) bH[j][kk] = rdB(b, 2 + j, kk);
    BAR(); WAITL0();
    __builtin_amdgcn_s_setprio(1); MF(aF, bH, 0, 1); __builtin_amdgcn_s_setprio(0);
    BAR();
    // P3: 8 reads (A mf4..7); B(t) region free since P2 barrier -> stage B(t+2)
#pragma unroll
    for (int i = 0; i < 4; ++i)
#pragma unroll
      for (int kk = 0; kk < 2; ++kk) aF[i][kk] = rdA(b, 4 + i, kk);
    stageB(0, tv + 2);
    stageB(1, tv + 2);
    BAR(); WAITL0();
    __builtin_amdgcn_s_setprio(1); MF(aF, bH, 1, 1); __builtin_amdgcn_s_setprio(0);
    BAR();
    // P4: 0 reads; A(t) region free since P3 barrier -> stage A(t+2); vmcnt(8)
    stageA(0, tv + 2);
    stageA(1, tv + 2);
    BAR(); WAITL0();
    __builtin_amdgcn_s_setprio(1); MF(aF, bL, 1, 0); __builtin_amdgcn_s_setprio(0);
    asm volatile("s_waitcnt vmcnt(8)" ::: "memory");
    BAR();
  };

  // prologue: issue tile0 then tile1 (FIFO order matters);
  // vmcnt(8) retires {B(0),A(0)}, leaves {B(1),A(1)} in flight.
  stageB(0, 0); stageB(1, 0); stageA(0, 0); stageA(1, 0);
  stageB(0, 1); stageB(1, 1); stageA(0, 1); stageA(1, 1);
  asm volatile("s_waitcnt vmcnt(8)" ::: "memory");
  BAR();

  for (int tv = 0; tv < 63; ++tv) tile_step(tv);   // stages t+2 = 2..64 (incl. LoRA)

  // peeled tile 63 (b=1): no stages; drain all at end
  {
    const int b = 1;
#pragma unroll
    for (int i = 0; i < 4; ++i)
#pragma unroll
      for (int kk = 0; kk < 2; ++kk) aF[i][kk] = rdA(b, i, kk);
#pragma unroll
    for (int j = 0; j < 2; ++j)
#pragma unroll
      for (int kk = 0; kk < 2; ++kk) bL[j][kk] = rdB(b, j, kk);
    BAR(); WAITL0();
    __builtin_amdgcn_s_setprio(1); MF(aF, bL, 0, 0); __builtin_amdgcn_s_setprio(0);
    BAR();
#pragma unroll
    for (int j = 0; j < 2; ++j)
#pragma unroll
      for (int kk = 0; kk < 2; ++kk) bH[j][kk] = rdB(b, 2 + j, kk);
    BAR(); WAITL0();
    __builtin_amdgcn_s_setprio(1); MF(aF, bH, 0, 1); __builtin_amdgcn_s_setprio(0);
    BAR();
#pragma unroll
    for (int i = 0; i < 4; ++i)
#pragma unroll
      for (int kk = 0; kk < 2; ++kk) aF[i][kk] = rdA(b, 4 + i, kk);
    BAR(); WAITL0();
    __builtin_amdgcn_s_setprio(1); MF(aF, bH, 1, 1); __builtin_amdgcn_s_setprio(0);
    BAR();
    __builtin_amdgcn_s_setprio(1); MF(aF, bL, 1, 0); __builtin_amdgcn_s_setprio(0);
    asm volatile("s_waitcnt vmcnt(0)" ::: "memory");
    BAR();
  }

  // LoRA tile 64 (buf 0): pure LDS reads + MFMA
  {
#pragma unroll
    for (int i = 0; i < 4; ++i)
#pragma unroll
      for (int kk = 0; kk < 2; ++kk) aF[i][kk] = rdA(0, i, kk);
#pragma unroll
    for (int j = 0; j < 2; ++j)
#pragma unroll
      for (int kk = 0; kk < 2; ++kk) { bL[j][kk] = rdB(0, j, kk); bH[j][kk] = rdB(0, 2 + j, kk); }
    MF(aF, bL, 0, 0); MF(aF, bH, 0, 1);
#pragma unroll
    for (int i = 0; i < 4; ++i)
#pragma unroll
      for (int kk = 0; kk < 2; ++kk) aF[i][kk] = rdA(0, 4 + i, kk);
    MF(aF, bH, 1, 1); MF(aF, bL, 1, 0);
  }

  // epilogue: + bias, store fp32
  float bb[4];
#pragma unroll
  for (int j = 0; j < 4; ++j) bb[j] = bias[n0 + wc * 64 + j * 16 + fr];
#pragma unroll
  for (int i = 0; i < 8; ++i) {
    const int row0 = m0 + wr * 128 + i * 16 + fg * 4;
#pragma unroll
    for (int j = 0; j < 4; ++j) {
      const int col = n0 + wc * 64 + j * 16 + fr;
#pragma unroll
      for (int q = 0; q < 4; ++q)
        out[(size_t)(row0 + q) * N + col] = acc[i][j][q] + bb[j];
    }
  }
}

extern "C" void kernel_launch(void* const* d_in, const int* in_sizes, int n_in,
                              void* d_out, int out_size, void* d_ws, size_t ws_size,
                              hipStream_t stream) {
  const float* x  = (const float*)d_in[0];   // [4,2048,4096] -> [8192,4096]
  const float* W  = (const float*)d_in[1];   // [4096,4096]
  const float* b  = (const float*)d_in[2];   // [4096]
  const float* lA = (const float*)d_in[3];   // [4096,16]
  const float* lB = (const float*)d_in[4];   // [16,4096]
  float* out = (float*)d_out;                // [8192,4096] fp32

  char* ws = (char*)d_ws;
  __bf16* Xb  = (__bf16*)ws;                                   // 67,108,864 B
  __bf16* Wb  = (__bf16*)(ws + 67108864);                      // 33,554,432 B
  __bf16* XAb = (__bf16*)(ws + 100663296);                     //  1,048,576 B
  __bf16* BlT = (__bf16*)(ws + 101711872);                     //    524,288 B

  xa_cvt<<<8192 / 16, 256, 0, stream>>>(x, lA, Xb, XAb);
  cvt_f32_bf16<<<1024, 256, 0, stream>>>(W, Wb, (long)4096 * 4096 / 8);
  blt64<<<4096 * 64 / 256, 256, 0, stream>>>(lB, BlT);

  gemm8<<<dim3(512), dim3(512), 0, stream>>>(Xb, Wb, XAb, BlT, b, out);
}

// Round 7
// 322.124 us; speedup vs baseline: 1.0496x; 1.0496x over previous
//
#include <hip/hip_runtime.h>

typedef float f32x4 __attribute__((ext_vector_type(4)));
typedef __bf16 bf16x8 __attribute__((ext_vector_type(8)));
typedef __bf16 bf16x4 __attribute__((ext_vector_type(4)));

#define GLOBAL_AS __attribute__((address_space(1)))
#define LDS_AS    __attribute__((address_space(3)))

static __device__ __forceinline__ void gload16(const void* g, void* l) {
  __builtin_amdgcn_global_load_lds((const GLOBAL_AS void*)g, (LDS_AS void*)l, 16, 0, 0);
}

#define BAR() __builtin_amdgcn_s_barrier()
#define WAITL0() do { asm volatile("s_waitcnt lgkmcnt(0)" ::: "memory"); __builtin_amdgcn_sched_barrier(0); } while (0)

// ---- fused: Xb = bf16(X); XAb = bf16(X @ lora_A) [8192][64], cols>=16 zero --
__global__ __launch_bounds__(256)
void xa_cvt(const float* __restrict__ X, const float* __restrict__ A,
            __bf16* __restrict__ Xb, __bf16* __restrict__ XAb) {
  constexpr int K = 4096, TM = 16, KC = 64;
  __shared__ float Xs[TM][68];
  __shared__ float At[16][68];
  const int t = threadIdx.x;
  const int m0 = blockIdx.x * TM;
  const int lrow = t >> 4, c4 = (t & 15) * 4;
  const int orow = t >> 4, oc = t & 15;
  const int akk = t >> 2, ar4 = (t & 3) * 4;
  f32x4 av = (f32x4)0.f;
  for (int k0 = 0; k0 < K; k0 += KC) {
    const float* gx = X + (size_t)(m0 + lrow) * K + k0 + c4;
    f32x4 u = *reinterpret_cast<const f32x4*>(gx);
    *reinterpret_cast<f32x4*>(&Xs[lrow][c4]) = u;
    bf16x4 p;
#pragma unroll
    for (int e = 0; e < 4; ++e) p[e] = (__bf16)u[e];
    *reinterpret_cast<bf16x4*>(Xb + (size_t)(m0 + lrow) * K + k0 + c4) = p;
    f32x4 a = *reinterpret_cast<const f32x4*>(A + (size_t)(k0 + akk) * 16 + ar4);
    At[ar4 + 0][akk] = a[0]; At[ar4 + 1][akk] = a[1];
    At[ar4 + 2][akk] = a[2]; At[ar4 + 3][akk] = a[3];
    __syncthreads();
#pragma unroll
    for (int q = 0; q < 16; ++q) {
      f32x4 xv = *reinterpret_cast<const f32x4*>(&Xs[orow][q * 4]);
      av += xv * *reinterpret_cast<const f32x4*>(&At[oc][q * 4]);
    }
    __syncthreads();
  }
  const float acc = av[0] + av[1] + av[2] + av[3];
  const size_t base = (size_t)(m0 + orow) * 64;
  XAb[base + oc] = (__bf16)acc;
#pragma unroll
  for (int z = 0; z < 3; ++z) XAb[base + 16 + z * 16 + oc] = (__bf16)0.f;
}

// ---------------- W -> bf16 (16B stores) ----------------
__global__ __launch_bounds__(256)
void cvt_f32_bf16(const float* __restrict__ in, __bf16* __restrict__ out, long n8) {
  long i = (long)blockIdx.x * blockDim.x + threadIdx.x;
  long stride = (long)gridDim.x * blockDim.x;
  for (; i < n8; i += stride) {
    f32x4 u = reinterpret_cast<const f32x4*>(in)[2 * i];
    f32x4 v = reinterpret_cast<const f32x4*>(in)[2 * i + 1];
    bf16x8 p;
#pragma unroll
    for (int e = 0; e < 4; ++e) { p[e] = (__bf16)u[e]; p[4 + e] = (__bf16)v[e]; }
    reinterpret_cast<bf16x8*>(out)[i] = p;
  }
}

// ------- BlT[col][k] = bf16(Bl[k][col]), [4096][64], k>=16 zero -------------
__global__ __launch_bounds__(256)
void blt64(const float* __restrict__ Bl, __bf16* __restrict__ BlT) {
  int idx = blockIdx.x * 256 + threadIdx.x;
  int col = idx >> 6, k = idx & 63;
  float v = (k < 16) ? Bl[(size_t)k * 4096 + col] : 0.f;
  BlT[idx] = (__bf16)v;
}

// ---------------- 256x256 8-phase GEMM: out = [Xb|XAb] @ [Wb|BlT]^T + b -----
// R4 schedule (proven 253us): one half-tile stage per phase —
// A0(t+1)@P1, A1(t+1)@P2, B0(t+2)@P3, B1(t+2)@P4, single vmcnt(4)/tile.
// Zero-conflict XOR swizzle, raw s_barrier, setprio, bijective XCD swizzle.
__global__ __launch_bounds__(512, 2)
void gemm8(const __bf16* __restrict__ Xb, const __bf16* __restrict__ Wb,
           const __bf16* __restrict__ XAb, const __bf16* __restrict__ BlT,
           const float* __restrict__ bias, float* __restrict__ out) {
  constexpr int N = 4096, K = 4096;
  __shared__ __align__(16) char sm[131072];
  char* Asm_ = sm;
  char* Bsm_ = sm + 65536;

  const int t = threadIdx.x;
  const int lane = t & 63, w = t >> 6;
  const int wr = w >> 2, wc = w & 3;
  const int fr = lane & 15, fg = lane >> 4;

  // bijective XCD swizzle: grid 512 = 32 mt x 16 nt; 2-mt inner group.
  const int bid = blockIdx.x;
  const int xcd = bid & 7, l = bid >> 3;
  const int mt = (xcd << 2) | ((l >> 4) & 2) | (l & 1);
  const int nt = (l >> 1) & 15;
  const int m0 = mt * 256, n0 = nt * 256;

  const int sRow = w * 16 + (lane >> 2);
  const int sColB = (((lane & 3) ^ ((lane >> 3) & 3)) << 4);   // inverse swizzle
  const int rdOff = fr * 64 + ((fg ^ ((fr >> 1) & 3)) << 4);
  const int rdOffA = wr * 16384 + rdOff;
  const int rdOffB = (wc >> 1) * 16384 + (wc & 1) * 8192 + rdOff;

  auto stageA = [&](int h, int tt) {
    char* dst = Asm_ + (tt & 1) * 32768 + h * 16384 + w * 2048;
    const char* g;
    if (tt < 64) g = (const char*)(Xb + (size_t)(m0 + h * 128 + sRow) * K + (size_t)tt * 64) + sColB;
    else         g = (const char*)(XAb + (size_t)(m0 + h * 128 + sRow) * 64) + sColB;
    gload16(g, dst);
    gload16(g + 64, dst + 1024);
  };
  auto stageB = [&](int h, int tt) {
    char* dst = Bsm_ + (tt & 1) * 32768 + h * 16384 + w * 2048;
    const char* g;
    if (tt < 64) g = (const char*)(Wb + (size_t)(n0 + h * 128 + sRow) * K + (size_t)tt * 64) + sColB;
    else         g = (const char*)(BlT + (size_t)(n0 + h * 128 + sRow) * 64) + sColB;
    gload16(g, dst);
    gload16(g + 64, dst + 1024);
  };

  auto rdA = [&](int b, int mf, int kk) -> bf16x8 {
    return *reinterpret_cast<const bf16x8*>(Asm_ + b * 32768 + (mf * 2 + kk) * 1024 + rdOffA);
  };
  auto rdB = [&](int b, int nf, int kk) -> bf16x8 {
    return *reinterpret_cast<const bf16x8*>(Bsm_ + b * 32768 + (nf * 2 + kk) * 1024 + rdOffB);
  };

  f32x4 acc[8][4];
#pragma unroll
  for (int i = 0; i < 8; ++i)
#pragma unroll
    for (int j = 0; j < 4; ++j) acc[i][j] = (f32x4)0.f;

  bf16x8 aF[4][2], bL[2][2], bH[2][2];

  auto MF = [&](bf16x8 (&af)[4][2], bf16x8 (&bf_)[2][2], int mi, int ni) {
#pragma unroll
    for (int i = 0; i < 4; ++i)
#pragma unroll
      for (int j = 0; j < 2; ++j)
#pragma unroll
        for (int kk = 0; kk < 2; ++kk)
          acc[mi * 4 + i][ni * 2 + j] = __builtin_amdgcn_mfma_f32_16x16x32_bf16(
              af[i][kk], bf_[j][kk], acc[mi * 4 + i][ni * 2 + j], 0, 0, 0);
  };

  auto tile_step = [&](int tv) {
    const int b = tv & 1;
    // P1: 12 ds_reads (A mf0..3, B nf0..1), stage A0(t+1)
#pragma unroll
    for (int i = 0; i < 4; ++i)
#pragma unroll
      for (int kk = 0; kk < 2; ++kk) aF[i][kk] = rdA(b, i, kk);
#pragma unroll
    for (int j = 0; j < 2; ++j)
#pragma unroll
      for (int kk = 0; kk < 2; ++kk) bL[j][kk] = rdB(b, j, kk);
    stageA(0, tv + 1);
    asm volatile("s_waitcnt lgkmcnt(8)" ::: "memory");   // partial drain of 12 reads
    BAR(); WAITL0();
    __builtin_amdgcn_s_setprio(1); MF(aF, bL, 0, 0); __builtin_amdgcn_s_setprio(0);
    BAR();
    // P2: 4 reads (B nf2..3), stage A1(t+1)
#pragma unroll
    for (int j = 0; j < 2; ++j)
#pragma unroll
      for (int kk = 0; kk < 2; ++kk) bH[j][kk] = rdB(b, 2 + j, kk);
    stageA(1, tv + 1);
    BAR(); WAITL0();
    __builtin_amdgcn_s_setprio(1); MF(aF, bH, 0, 1); __builtin_amdgcn_s_setprio(0);
    BAR();
    // P3: 8 reads (A mf4..7), stage B0(t+2)
#pragma unroll
    for (int i = 0; i < 4; ++i)
#pragma unroll
      for (int kk = 0; kk < 2; ++kk) aF[i][kk] = rdA(b, 4 + i, kk);
    if (tv + 2 <= 64) stageB(0, tv + 2);
    BAR(); WAITL0();
    __builtin_amdgcn_s_setprio(1); MF(aF, bH, 1, 1); __builtin_amdgcn_s_setprio(0);
    BAR();
    // P4: 0 reads, stage B1(t+2), counted vmcnt checkpoint
    if (tv + 2 <= 64) stageB(1, tv + 2);
    BAR(); WAITL0();
    __builtin_amdgcn_s_setprio(1); MF(aF, bL, 1, 0); __builtin_amdgcn_s_setprio(0);
    asm volatile("s_waitcnt vmcnt(4)" ::: "memory");
    BAR();
  };

  // prologue: A(0),B(0),B(1) issued; vmcnt(4) retires A(0),B(0); B(1) in flight
  stageA(0, 0); stageA(1, 0); stageB(0, 0); stageB(1, 0); stageB(0, 1); stageB(1, 1);
  asm volatile("s_waitcnt vmcnt(4)" ::: "memory");
  BAR();

  for (int tp = 0; tp < 32; ++tp) { tile_step(2 * tp); tile_step(2 * tp + 1); }

  // LoRA tile 64 (buf 0): drain everything, then pure-LDS MFMA
  asm volatile("s_waitcnt vmcnt(0)" ::: "memory");
  BAR();
  {
#pragma unroll
    for (int i = 0; i < 4; ++i)
#pragma unroll
      for (int kk = 0; kk < 2; ++kk) aF[i][kk] = rdA(0, i, kk);
#pragma unroll
    for (int j = 0; j < 2; ++j)
#pragma unroll
      for (int kk = 0; kk < 2; ++kk) { bL[j][kk] = rdB(0, j, kk); bH[j][kk] = rdB(0, 2 + j, kk); }
    MF(aF, bL, 0, 0); MF(aF, bH, 0, 1);
#pragma unroll
    for (int i = 0; i < 4; ++i)
#pragma unroll
      for (int kk = 0; kk < 2; ++kk) aF[i][kk] = rdA(0, 4 + i, kk);
    MF(aF, bH, 1, 1); MF(aF, bL, 1, 0);
  }

  // epilogue: + bias, store fp32
  float bb[4];
#pragma unroll
  for (int j = 0; j < 4; ++j) bb[j] = bias[n0 + wc * 64 + j * 16 + fr];
#pragma unroll
  for (int i = 0; i < 8; ++i) {
    const int row0 = m0 + wr * 128 + i * 16 + fg * 4;
#pragma unroll
    for (int j = 0; j < 4; ++j) {
      const int col = n0 + wc * 64 + j * 16 + fr;
#pragma unroll
      for (int q = 0; q < 4; ++q)
        out[(size_t)(row0 + q) * N + col] = acc[i][j][q] + bb[j];
    }
  }
}

extern "C" void kernel_launch(void* const* d_in, const int* in_sizes, int n_in,
                              void* d_out, int out_size, void* d_ws, size_t ws_size,
                              hipStream_t stream) {
  const float* x  = (const float*)d_in[0];   // [4,2048,4096] -> [8192,4096]
  const float* W  = (const float*)d_in[1];   // [4096,4096]
  const float* b  = (const float*)d_in[2];   // [4096]
  const float* lA = (const float*)d_in[3];   // [4096,16]
  const float* lB = (const float*)d_in[4];   // [16,4096]
  float* out = (float*)d_out;                // [8192,4096] fp32

  char* ws = (char*)d_ws;
  __bf16* Xb  = (__bf16*)ws;                                   // 67,108,864 B
  __bf16* Wb  = (__bf16*)(ws + 67108864);                      // 33,554,432 B
  __bf16* XAb = (__bf16*)(ws + 100663296);                     //  1,048,576 B
  __bf16* BlT = (__bf16*)(ws + 101711872);                     //    524,288 B

  xa_cvt<<<8192 / 16, 256, 0, stream>>>(x, lA, Xb, XAb);
  cvt_f32_bf16<<<1024, 256, 0, stream>>>(W, Wb, (long)4096 * 4096 / 8);
  blt64<<<4096 * 64 / 256, 256, 0, stream>>>(lB, BlT);

  gemm8<<<dim3(512), dim3(512), 0, stream>>>(Xb, Wb, XAb, BlT, b, out);
}

// Round 8
// 315.843 us; speedup vs baseline: 1.0705x; 1.0199x over previous
//
#include <hip/hip_runtime.h>

typedef float f32x4 __attribute__((ext_vector_type(4)));
typedef __bf16 bf16x8 __attribute__((ext_vector_type(8)));
typedef __bf16 bf16x4 __attribute__((ext_vector_type(4)));

#define GLOBAL_AS __attribute__((address_space(1)))
#define LDS_AS    __attribute__((address_space(3)))

static __device__ __forceinline__ void gload16(const void* g, void* l) {
  __builtin_amdgcn_global_load_lds((const GLOBAL_AS void*)g, (LDS_AS void*)l, 16, 0, 0);
}

#define BAR() __builtin_amdgcn_s_barrier()
#define WAITL0() do { asm volatile("s_waitcnt lgkmcnt(0)" ::: "memory"); __builtin_amdgcn_sched_barrier(0); } while (0)

// ---- merged prep: blocks 0-511: Xb=bf16(X), XAb=bf16(X@lora_A);
//      blocks 512-1535: Wb=bf16(W); blocks 1536-2559: BlT[col][k] ----
__global__ __launch_bounds__(256)
void prep_all(const float* __restrict__ X, const float* __restrict__ A,
              const float* __restrict__ W, const float* __restrict__ Bl,
              __bf16* __restrict__ Xb, __bf16* __restrict__ XAb,
              __bf16* __restrict__ Wb, __bf16* __restrict__ BlT) {
  __shared__ float Xs[16][68];
  __shared__ float At[16][68];
  const int bid = blockIdx.x;
  const int t = threadIdx.x;
  if (bid < 512) {
    // fused X convert + XA dot (TM=16, KC=64)
    constexpr int K = 4096, KC = 64;
    const int m0 = bid * 16;
    const int lrow = t >> 4, c4 = (t & 15) * 4;
    const int orow = t >> 4, oc = t & 15;
    const int akk = t >> 2, ar4 = (t & 3) * 4;
    f32x4 av = (f32x4)0.f;
    for (int k0 = 0; k0 < K; k0 += KC) {
      f32x4 u = *reinterpret_cast<const f32x4*>(X + (size_t)(m0 + lrow) * K + k0 + c4);
      *reinterpret_cast<f32x4*>(&Xs[lrow][c4]) = u;
      bf16x4 p;
#pragma unroll
      for (int e = 0; e < 4; ++e) p[e] = (__bf16)u[e];
      *reinterpret_cast<bf16x4*>(Xb + (size_t)(m0 + lrow) * K + k0 + c4) = p;
      f32x4 a = *reinterpret_cast<const f32x4*>(A + (size_t)(k0 + akk) * 16 + ar4);
      At[ar4 + 0][akk] = a[0]; At[ar4 + 1][akk] = a[1];
      At[ar4 + 2][akk] = a[2]; At[ar4 + 3][akk] = a[3];
      __syncthreads();
#pragma unroll
      for (int q = 0; q < 16; ++q) {
        f32x4 xv = *reinterpret_cast<const f32x4*>(&Xs[orow][q * 4]);
        av += xv * *reinterpret_cast<const f32x4*>(&At[oc][q * 4]);
      }
      __syncthreads();
    }
    const float acc = av[0] + av[1] + av[2] + av[3];
    const size_t base = (size_t)(m0 + orow) * 64;
    XAb[base + oc] = (__bf16)acc;
#pragma unroll
    for (int z = 0; z < 3; ++z) XAb[base + 16 + z * 16 + oc] = (__bf16)0.f;
  } else if (bid < 1536) {
    // W -> bf16, 16B stores; 1024 blocks x 256 thr x 8 chunks = 2,097,152 x8
    long base = (long)(bid - 512) * 256 + t;
#pragma unroll
    for (int r = 0; r < 8; ++r) {
      long i = base + (long)r * 262144;
      f32x4 u = reinterpret_cast<const f32x4*>(W)[2 * i];
      f32x4 v = reinterpret_cast<const f32x4*>(W)[2 * i + 1];
      bf16x8 p;
#pragma unroll
      for (int e = 0; e < 4; ++e) { p[e] = (__bf16)u[e]; p[4 + e] = (__bf16)v[e]; }
      reinterpret_cast<bf16x8*>(Wb)[i] = p;
    }
  } else {
    // BlT[col][k] = bf16(Bl[k][col]), [4096][64], k>=16 zero
    int idx = (bid - 1536) * 256 + t;
    int col = idx >> 6, k = idx & 63;
    float v = (k < 16) ? Bl[(size_t)k * 4096 + col] : 0.f;
    BlT[idx] = (__bf16)v;
  }
}

// ---------------- 256x256 8-phase GEMM: out = [Xb|XAb] @ [Wb|BlT]^T + b -----
// R4 schedule (proven): A0(t+1)@P1, A1(t+1)@P2, B0(t+2)@P3, B1(t+2)@P4,
// single vmcnt(4)/tile. Steady loop tv=0..61 branch-free with pointer-bump;
// tiles 62/63 peeled for the LoRA (XAb/BlT) staging.
__global__ __launch_bounds__(512, 2)
void gemm8(const __bf16* __restrict__ Xb, const __bf16* __restrict__ Wb,
           const __bf16* __restrict__ XAb, const __bf16* __restrict__ BlT,
           const float* __restrict__ bias, float* __restrict__ out) {
  constexpr int N = 4096, K = 4096;
  __shared__ __align__(16) char sm[131072];
  char* Asm_ = sm;
  char* Bsm_ = sm + 65536;

  const int t = threadIdx.x;
  const int lane = t & 63, w = t >> 6;
  const int wr = w >> 2, wc = w & 3;
  const int fr = lane & 15, fg = lane >> 4;

  // bijective XCD swizzle: grid 512 = 32 mt x 16 nt; 2-mt inner group.
  const int bid = blockIdx.x;
  const int xcd = bid & 7, l = bid >> 3;
  const int mt = (xcd << 2) | ((l >> 4) & 2) | (l & 1);
  const int nt = (l >> 1) & 15;
  const int m0 = mt * 256, n0 = nt * 256;

  const int sRow = w * 16 + (lane >> 2);
  const int sColB = (((lane & 3) ^ ((lane >> 3) & 3)) << 4);   // inverse swizzle
  const int rdOff = fr * 64 + ((fg ^ ((fr >> 1) & 3)) << 4);
  const int rdOffA = wr * 16384 + rdOff;
  const int rdOffB = (wc >> 1) * 16384 + (wc & 1) * 8192 + rdOff;

  // per-thread global byte pointers (row stride K*2 = 8192 B)
  const char* gA0 = (const char*)Xb + (size_t)(m0 + sRow) * 8192 + sColB;
  const char* gA1 = (const char*)Xb + (size_t)(m0 + 128 + sRow) * 8192 + sColB;
  const char* gB0 = (const char*)Wb + (size_t)(n0 + sRow) * 8192 + sColB;
  const char* gB1 = (const char*)Wb + (size_t)(n0 + 128 + sRow) * 8192 + sColB;

  auto stage2 = [&](const char* g, char* dst) { gload16(g, dst); gload16(g + 64, dst + 1024); };

  auto rdA = [&](int b, int mf, int kk) -> bf16x8 {
    return *reinterpret_cast<const bf16x8*>(Asm_ + b * 32768 + (mf * 2 + kk) * 1024 + rdOffA);
  };
  auto rdB = [&](int b, int nf, int kk) -> bf16x8 {
    return *reinterpret_cast<const bf16x8*>(Bsm_ + b * 32768 + (nf * 2 + kk) * 1024 + rdOffB);
  };

  f32x4 acc[8][4];
#pragma unroll
  for (int i = 0; i < 8; ++i)
#pragma unroll
    for (int j = 0; j < 4; ++j) acc[i][j] = (f32x4)0.f;

  bf16x8 aF[4][2], bL[2][2], bH[2][2];

  auto MF = [&](bf16x8 (&af)[4][2], bf16x8 (&bf_)[2][2], int mi, int ni) {
#pragma unroll
    for (int i = 0; i < 4; ++i)
#pragma unroll
      for (int j = 0; j < 2; ++j)
#pragma unroll
        for (int kk = 0; kk < 2; ++kk)
          acc[mi * 4 + i][ni * 2 + j] = __builtin_amdgcn_mfma_f32_16x16x32_bf16(
              af[i][kk], bf_[j][kk], acc[mi * 4 + i][ni * 2 + j], 0, 0, 0);
  };

  // hoisted bias loads
  float bb[4];
#pragma unroll
  for (int j = 0; j < 4; ++j) bb[j] = bias[n0 + wc * 64 + j * 16 + fr];

  // prologue: A(0), B(0), B(1); vmcnt(4) retires A(0),B(0); B(1) in flight
  stage2(gA0, Asm_ + w * 2048);
  stage2(gA1, Asm_ + 16384 + w * 2048);
  stage2(gB0, Bsm_ + w * 2048);
  stage2(gB1, Bsm_ + 16384 + w * 2048);
  stage2(gB0 + 128, Bsm_ + 32768 + w * 2048);
  stage2(gB1 + 128, Bsm_ + 32768 + 16384 + w * 2048);
  asm volatile("s_waitcnt vmcnt(4)" ::: "memory");
  BAR();

  // steady-loop bump pointers: A at tile 1, B at tile 2
  const char* pA0 = gA0 + 128;
  const char* pA1 = gA1 + 128;
  const char* pB0 = gB0 + 256;
  const char* pB1 = gB1 + 256;

  auto tile_step = [&](int b) {   // b = tv&1 (literal at call sites)
    char* dstA = Asm_ + (b ^ 1) * 32768 + w * 2048;
    char* dstB = Bsm_ + b * 32768 + w * 2048;
    // P1: 12 reads (A mf0..3, B nf0..1), stage A0(t+1)
#pragma unroll
    for (int i = 0; i < 4; ++i)
#pragma unroll
      for (int kk = 0; kk < 2; ++kk) aF[i][kk] = rdA(b, i, kk);
#pragma unroll
    for (int j = 0; j < 2; ++j)
#pragma unroll
      for (int kk = 0; kk < 2; ++kk) bL[j][kk] = rdB(b, j, kk);
    stage2(pA0, dstA); pA0 += 128;
    asm volatile("s_waitcnt lgkmcnt(8)" ::: "memory");
    BAR(); WAITL0();
    __builtin_amdgcn_s_setprio(1); MF(aF, bL, 0, 0); __builtin_amdgcn_s_setprio(0);
    BAR();
    // P2: 4 reads (B nf2..3), stage A1(t+1)
#pragma unroll
    for (int j = 0; j < 2; ++j)
#pragma unroll
      for (int kk = 0; kk < 2; ++kk) bH[j][kk] = rdB(b, 2 + j, kk);
    stage2(pA1, dstA + 16384); pA1 += 128;
    BAR(); WAITL0();
    __builtin_amdgcn_s_setprio(1); MF(aF, bH, 0, 1); __builtin_amdgcn_s_setprio(0);
    BAR();
    // P3: 8 reads (A mf4..7), stage B0(t+2)
#pragma unroll
    for (int i = 0; i < 4; ++i)
#pragma unroll
      for (int kk = 0; kk < 2; ++kk) aF[i][kk] = rdA(b, 4 + i, kk);
    stage2(pB0, dstB); pB0 += 128;
    BAR(); WAITL0();
    __builtin_amdgcn_s_setprio(1); MF(aF, bH, 1, 1); __builtin_amdgcn_s_setprio(0);
    BAR();
    // P4: 0 reads, stage B1(t+2), counted vmcnt checkpoint
    stage2(pB1, dstB + 16384); pB1 += 128;
    BAR(); WAITL0();
    __builtin_amdgcn_s_setprio(1); MF(aF, bL, 1, 0); __builtin_amdgcn_s_setprio(0);
    asm volatile("s_waitcnt vmcnt(4)" ::: "memory");
    BAR();
  };

  for (int tp = 0; tp < 31; ++tp) { tile_step(0); tile_step(1); }   // tv = 0..61

  // peel tv=62 (b=0): A(63) normal, B(64) = BlT
  {
    const char* gBl0 = (const char*)BlT + (size_t)(n0 + sRow) * 128 + sColB;
    const char* gBl1 = (const char*)BlT + (size_t)(n0 + 128 + sRow) * 128 + sColB;
    char* dstA = Asm_ + 32768 + w * 2048;
    char* dstB = Bsm_ + w * 2048;
#pragma unroll
    for (int i = 0; i < 4; ++i)
#pragma unroll
      for (int kk = 0; kk < 2; ++kk) aF[i][kk] = rdA(0, i, kk);
#pragma unroll
    for (int j = 0; j < 2; ++j)
#pragma unroll
      for (int kk = 0; kk < 2; ++kk) bL[j][kk] = rdB(0, j, kk);
    stage2(pA0, dstA);
    asm volatile("s_waitcnt lgkmcnt(8)" ::: "memory");
    BAR(); WAITL0();
    __builtin_amdgcn_s_setprio(1); MF(aF, bL, 0, 0); __builtin_amdgcn_s_setprio(0);
    BAR();
#pragma unroll
    for (int j = 0; j < 2; ++j)
#pragma unroll
      for (int kk = 0; kk < 2; ++kk) bH[j][kk] = rdB(0, 2 + j, kk);
    stage2(pA1, dstA + 16384);
    BAR(); WAITL0();
    __builtin_amdgcn_s_setprio(1); MF(aF, bH, 0, 1); __builtin_amdgcn_s_setprio(0);
    BAR();
#pragma unroll
    for (int i = 0; i < 4; ++i)
#pragma unroll
      for (int kk = 0; kk < 2; ++kk) aF[i][kk] = rdA(0, 4 + i, kk);
    stage2(gBl0, dstB);
    BAR(); WAITL0();
    __builtin_amdgcn_s_setprio(1); MF(aF, bH, 1, 1); __builtin_amdgcn_s_setprio(0);
    BAR();
    stage2(gBl1, dstB + 16384);
    BAR(); WAITL0();
    __builtin_amdgcn_s_setprio(1); MF(aF, bL, 1, 0); __builtin_amdgcn_s_setprio(0);
    asm volatile("s_waitcnt vmcnt(4)" ::: "memory");
    BAR();
  }

  // peel tv=63 (b=1): A(64) = XAb; no B stage
  {
    const char* gXA0 = (const char*)XAb + (size_t)(m0 + sRow) * 128 + sColB;
    const char* gXA1 = (const char*)XAb + (size_t)(m0 + 128 + sRow) * 128 + sColB;
    char* dstA = Asm_ + w * 2048;
#pragma unroll
    for (int i = 0; i < 4; ++i)
#pragma unroll
      for (int kk = 0; kk < 2; ++kk) aF[i][kk] = rdA(1, i, kk);
#pragma unroll
    for (int j = 0; j < 2; ++j)
#pragma unroll
      for (int kk = 0; kk < 2; ++kk) bL[j][kk] = rdB(1, j, kk);
    stage2(gXA0, dstA);
    asm volatile("s_waitcnt lgkmcnt(8)" ::: "memory");
    BAR(); WAITL0();
    __builtin_amdgcn_s_setprio(1); MF(aF, bL, 0, 0); __builtin_amdgcn_s_setprio(0);
    BAR();
#pragma unroll
    for (int j = 0; j < 2; ++j)
#pragma unroll
      for (int kk = 0; kk < 2; ++kk) bH[j][kk] = rdB(1, 2 + j, kk);
    stage2(gXA1, dstA + 16384);
    BAR(); WAITL0();
    __builtin_amdgcn_s_setprio(1); MF(aF, bH, 0, 1); __builtin_amdgcn_s_setprio(0);
    BAR();
#pragma unroll
    for (int i = 0; i < 4; ++i)
#pragma unroll
      for (int kk = 0; kk < 2; ++kk) aF[i][kk] = rdA(1, 4 + i, kk);
    BAR(); WAITL0();
    __builtin_amdgcn_s_setprio(1); MF(aF, bH, 1, 1); __builtin_amdgcn_s_setprio(0);
    BAR();
    __builtin_amdgcn_s_setprio(1); MF(aF, bL, 1, 0); __builtin_amdgcn_s_setprio(0);
    BAR();
  }

  // LoRA tile 64 (buf 0): full drain, pure-LDS MFMA
  asm volatile("s_waitcnt vmcnt(0)" ::: "memory");
  BAR();
  {
#pragma unroll
    for (int i = 0; i < 4; ++i)
#pragma unroll
      for (int kk = 0; kk < 2; ++kk) aF[i][kk] = rdA(0, i, kk);
#pragma unroll
    for (int j = 0; j < 2; ++j)
#pragma unroll
      for (int kk = 0; kk < 2; ++kk) { bL[j][kk] = rdB(0, j, kk); bH[j][kk] = rdB(0, 2 + j, kk); }
    MF(aF, bL, 0, 0); MF(aF, bH, 0, 1);
#pragma unroll
    for (int i = 0; i < 4; ++i)
#pragma unroll
      for (int kk = 0; kk < 2; ++kk) aF[i][kk] = rdA(0, 4 + i, kk);
    MF(aF, bH, 1, 1); MF(aF, bL, 1, 0);
  }

  // epilogue: + bias, store fp32
#pragma unroll
  for (int i = 0; i < 8; ++i) {
    const int row0 = m0 + wr * 128 + i * 16 + fg * 4;
#pragma unroll
    for (int j = 0; j < 4; ++j) {
      const int col = n0 + wc * 64 + j * 16 + fr;
#pragma unroll
      for (int q = 0; q < 4; ++q)
        out[(size_t)(row0 + q) * N + col] = acc[i][j][q] + bb[j];
    }
  }
}

extern "C" void kernel_launch(void* const* d_in, const int* in_sizes, int n_in,
                              void* d_out, int out_size, void* d_ws, size_t ws_size,
                              hipStream_t stream) {
  const float* x  = (const float*)d_in[0];   // [4,2048,4096] -> [8192,4096]
  const float* W  = (const float*)d_in[1];   // [4096,4096]
  const float* b  = (const float*)d_in[2];   // [4096]
  const float* lA = (const float*)d_in[3];   // [4096,16]
  const float* lB = (const float*)d_in[4];   // [16,4096]
  float* out = (float*)d_out;                // [8192,4096] fp32

  char* ws = (char*)d_ws;
  __bf16* Xb  = (__bf16*)ws;                                   // 67,108,864 B
  __bf16* Wb  = (__bf16*)(ws + 67108864);                      // 33,554,432 B
  __bf16* XAb = (__bf16*)(ws + 100663296);                     //  1,048,576 B
  __bf16* BlT = (__bf16*)(ws + 101711872);                     //    524,288 B

  prep_all<<<2560, 256, 0, stream>>>(x, lA, W, lB, Xb, XAb, Wb, BlT);
  gemm8<<<dim3(512), dim3(512), 0, stream>>>(Xb, Wb, XAb, BlT, b, out);
}